// Round 1
// baseline (1542.531 us; speedup 1.0000x reference)
//
#include <hip/hip_runtime.h>

#define NROWS 8192
#define NCOLS 32000

// ---------------- Kernel A: per-row online softmax stats ----------------
// One block (256 threads) per row. Computes score = 1/sum(exp(x-m)) and
// loss = m + log(s) - x[target].
__global__ __launch_bounds__(256) void row_stats_kernel(
    const float* __restrict__ x, const int* __restrict__ tgt,
    float* __restrict__ scores, float* __restrict__ losses) {
  const int row = blockIdx.x;
  const int tid = threadIdx.x;
  const float* xr = x + (size_t)row * NCOLS;

  float xy = 0.0f;
  if (tid == 0) xy = xr[tgt[row]];

  // online max + sum-exp, float4 vectorized (row stride 128000 B -> 16B aligned)
  float m = -3.0e38f;
  float s = 0.0f;
  const float4* xr4 = (const float4*)xr;
  for (int v = tid; v < NCOLS / 4; v += 256) {
    float4 q = xr4[v];
    float e[4] = {q.x, q.y, q.z, q.w};
#pragma unroll
    for (int k = 0; k < 4; k++) {
      float f = e[k];
      if (f > m) {
        s = s * __expf(m - f) + 1.0f;
        m = f;
      } else {
        s += __expf(f - m);
      }
    }
  }

  // wave (64-lane) reduction of (m, s)
#pragma unroll
  for (int off = 32; off > 0; off >>= 1) {
    float om = __shfl_down(m, off);
    float os = __shfl_down(s, off);
    if (om > m) {
      s = s * __expf(m - om) + os;
      m = om;
    } else {
      s += os * __expf(om - m);
    }
  }

  __shared__ float sm[4], ss[4];
  const int wave = tid >> 6, lane = tid & 63;
  if (lane == 0) { sm[wave] = m; ss[wave] = s; }
  __syncthreads();
  if (tid == 0) {
#pragma unroll
    for (int w = 1; w < 4; w++) {
      float om = sm[w], os = ss[w];
      if (om > m) {
        s = s * __expf(m - om) + os;
        m = om;
      } else {
        s += os * __expf(om - m);
      }
    }
    float lse = m + __logf(s);
    scores[row] = __expf(m - lse);  // = max softmax prob
    losses[row] = lse - xy;         // cross-entropy
  }
}

// ---------------- Kernel B: harmonic-tail weight table (fp64) ----------------
// w[r] = sum_{k=r+1}^{NROWS-1} 1/k.  Also zero-inits the fp64 accumulator.
__global__ __launch_bounds__(256) void harmonic_kernel(double* __restrict__ w,
                                                       double* __restrict__ acc) {
  __shared__ double chunk[256];
  __shared__ double pref[257];
  const int t = threadIdx.x;
  const int base = t * (NROWS / 256);  // 32 entries per thread
  double cs = 0.0;
  for (int k = 0; k < NROWS / 256; k++) {
    int r = base + k;
    if (r >= 1) cs += 1.0 / (double)r;
  }
  chunk[t] = cs;
  __syncthreads();
  if (t == 0) {
    double run = 0.0;
    for (int i = 0; i < 256; i++) { pref[i] = run; run += chunk[i]; }
    pref[256] = run;  // H_{NROWS-1}
    acc[0] = 0.0;
  }
  __syncthreads();
  const double total = pref[256];
  double run = pref[t];
  for (int k = 0; k < NROWS / 256; k++) {
    int r = base + k;
    if (r >= 1) run += 1.0 / (double)r;
    w[r] = total - run;  // H_{N-1} - H_r
  }
}

// ---------------- Kernel C: rank by counting + weighted accumulate ----------------
// Block i counts #(score_j > score_i) + #(score_j == score_i && j < i)
// (matches stable argsort(-scores)), then adds loss_i * w[rank] into fp64 acc.
__global__ __launch_bounds__(256) void rank_reduce_kernel(
    const float* __restrict__ scores, const float* __restrict__ losses,
    const double* __restrict__ w, double* __restrict__ acc) {
  const int i = blockIdx.x;
  const int tid = threadIdx.x;
  const float si = scores[i];
  int cnt = 0;
  for (int j = tid; j < NROWS; j += 256) {
    float sj = scores[j];
    cnt += (sj > si) || (sj == si && j < i);
  }
#pragma unroll
  for (int off = 32; off > 0; off >>= 1) cnt += __shfl_down(cnt, off);
  __shared__ int sc[4];
  const int wave = tid >> 6, lane = tid & 63;
  if (lane == 0) sc[wave] = cnt;
  __syncthreads();
  if (tid == 0) {
    int rank = sc[0] + sc[1] + sc[2] + sc[3];
    double contrib = (double)losses[i] * w[rank];
    atomicAdd(acc, contrib);
  }
}

// ---------------- Kernel D: finalize ----------------
__global__ void finalize_kernel(const double* __restrict__ acc, float* __restrict__ out) {
  out[0] = (float)(acc[0] / (double)NROWS);
}

extern "C" void kernel_launch(void* const* d_in, const int* in_sizes, int n_in,
                              void* d_out, int out_size, void* d_ws, size_t ws_size,
                              hipStream_t stream) {
  const float* input = (const float*)d_in[0];
  const int* target = (const int*)d_in[1];
  float* out = (float*)d_out;

  // workspace layout (ws re-poisoned each call; everything rewritten each call)
  char* ws = (char*)d_ws;
  double* w = (double*)ws;                        // 8192 * 8 = 65536 B
  double* acc = (double*)(ws + 65536);            // 8 B
  float* scores = (float*)(ws + 65552);           // 8192 * 4 = 32768 B
  float* losses = (float*)(ws + 65552 + 32768);   // 8192 * 4

  row_stats_kernel<<<NROWS, 256, 0, stream>>>(input, target, scores, losses);
  harmonic_kernel<<<1, 256, 0, stream>>>(w, acc);
  rank_reduce_kernel<<<NROWS, 256, 0, stream>>>(scores, losses, w, acc);
  finalize_kernel<<<1, 1, 0, stream>>>(acc, out);
}